// Round 11
// baseline (654.054 us; speedup 1.0000x reference)
//
#include <hip/hip_runtime.h>
#include <hip/hip_cooperative_groups.h>

namespace cg = cooperative_groups;

#define N_NODES 100000
#define N_EDGES 800000
#define FIN 64
#define HID 128
#define NB1 391   // ceil(N_NODES/256)
#define GT (NB1 * 256)                     // 100096 threads in the cooperative grid
#define SRCS_CAP (N_EDGES + 3 * N_NODES)   // padded CSR capacity (pad to multiple of 4 per node)

typedef unsigned short ushort_t;
typedef __attribute__((ext_vector_type(8))) short short8;   // 8 bf16 = 4 VGPRs (MFMA A/B frag)
typedef __attribute__((ext_vector_type(16))) float fx16;    // 32x32 MFMA C/D frag
typedef __attribute__((ext_vector_type(4))) unsigned short us4;

__device__ inline ushort_t f2bf(float f) {   // RNE fp32 -> bf16
    unsigned u = __float_as_uint(f);
    u += 0x7fffu + ((u >> 16) & 1u);
    return (ushort_t)(u >> 16);
}

__device__ inline void upadd(float* acc, uint4 A) {   // accumulate 8 bf16 of a 16B chunk
    acc[0] += __uint_as_float(A.x << 16);
    acc[1] += __uint_as_float(A.x & 0xffff0000u);
    acc[2] += __uint_as_float(A.y << 16);
    acc[3] += __uint_as_float(A.y & 0xffff0000u);
    acc[4] += __uint_as_float(A.z << 16);
    acc[5] += __uint_as_float(A.z & 0xffff0000u);
    acc[6] += __uint_as_float(A.w << 16);
    acc[7] += __uint_as_float(A.w & 0xffff0000u);
}

// ------- cooperative CSR build + dtype conversion (replaces 8 launches) -------
// Phases split by grid.sync(): P0 zero+cvt+detect | P1 hist | P2 scan1 | P3 scan2
// | P4 scan3 | P5 scatter.  391 blocks x 256 threads — all co-resident.
// detect: block-0 tree reduction, plain store to flag (no init race; PROVEN device
// probe — do NOT replace with in_sizes heuristics, r8/r9 aborts).
__global__ void __launch_bounds__(256) csr_kernel(
    const int* __restrict__ ei, const float* __restrict__ x,
    const float* __restrict__ W1rel, const float* __restrict__ W1root,
    const float* __restrict__ W2rel, const float* __restrict__ W2root,
    int* __restrict__ deg, int* __restrict__ flag, int* __restrict__ srcs,
    int* __restrict__ rank, int* __restrict__ off, int* __restrict__ bsums,
    ushort_t* __restrict__ xb, ushort_t* __restrict__ h1b,
    ushort_t* __restrict__ Wb1, ushort_t* __restrict__ Wb2) {
    cg::grid_group grid = cg::this_grid();
    __shared__ int s[512];
    int t = threadIdx.x;
    int gtid = blockIdx.x * 256 + t;

    // ---- P0: zero deg, sentinel-fill srcs, cvt x/weights/zero-rows, block0 detect ----
    if (gtid < N_NODES) deg[gtid] = 0;
    for (int k = gtid; k < SRCS_CAP; k += GT) srcs[k] = N_NODES;
    for (int i = gtid; i < N_NODES * FIN / 4; i += GT) {
        float4 v = ((const float4*)x)[i];
        us4 o = {f2bf(v.x), f2bf(v.y), f2bf(v.z), f2bf(v.w)};
        ((us4*)xb)[i] = o;
    }
    us4 z = {0, 0, 0, 0};
    if (gtid < 16) ((us4*)xb)[(size_t)N_NODES * 16 + gtid] = z;          // xb zero row
    if (gtid >= 16 && gtid < 48) ((us4*)h1b)[(size_t)N_NODES * 32 + (gtid - 16)] = z;  // h1b zero row
    if (gtid < HID * HID) {
        int n = gtid >> 7, k = gtid & 127;
        float v = (k < FIN) ? W1rel[n * FIN + k] : W1root[n * FIN + (k - FIN)];
        Wb1[gtid] = f2bf(v);
    }
    if (gtid < HID * 2 * HID) {
        int n = gtid >> 8, k = gtid & 255;
        float v = (k < HID) ? W2rel[n * HID + k] : W2root[n * HID + (k - HID)];
        Wb2[gtid] = f2bf(v);
    }
    if (blockIdx.x == 0) {           // int64 little-endian => odd words all 0
        int bad = 0;
        for (int i = t; i < 8192; i += 256) bad |= ei[2 * i + 1];
        s[t] = bad;
        __syncthreads();
        for (int d = 128; d > 0; d >>= 1) {
            if (t < d) s[t] |= s[t + d];
            __syncthreads();
        }
        if (t == 0) *flag = (s[0] != 0) ? 1 : 0;   // 1 => int32 layout
        __syncthreads();
    }
    __threadfence();
    grid.sync();

    // ---- P1: hist (grid-stride, ~8 edges/thread) ----
    int is32 = *flag;
    for (int e = gtid; e < N_EDGES; e += GT) {
        int d = is32 ? ei[N_EDGES + e] : ei[2 * (N_EDGES + e)];
        rank[e] = atomicAdd(&deg[d], 1);
    }
    __threadfence();
    grid.sync();

    // ---- P2: scan1 (per-block inclusive scan of padded degrees) ----
    {
        int v = (gtid < N_NODES) ? ((deg[gtid] + 3) & ~3) : 0;   // padded degree (x4)
        s[t] = v;
        __syncthreads();
        for (int d = 1; d < 256; d <<= 1) {
            int w = (t >= d) ? s[t - d] : 0;
            __syncthreads();
            s[t] += w;
            __syncthreads();
        }
        if (gtid < N_NODES) off[gtid] = s[t] - v;
        if (t == 255) bsums[blockIdx.x] = s[255];
    }
    __threadfence();
    grid.sync();

    // ---- P3: scan2 (block 0: 391 block sums, pair-scan with 256 threads) ----
    if (blockIdx.x == 0) {
        int v0 = (2 * t < NB1) ? bsums[2 * t] : 0;
        int v1 = (2 * t + 1 < NB1) ? bsums[2 * t + 1] : 0;
        int pair = v0 + v1;
        s[t] = pair;
        __syncthreads();
        for (int d = 1; d < 256; d <<= 1) {
            int w = (t >= d) ? s[t - d] : 0;
            __syncthreads();
            s[t] += w;
            __syncthreads();
        }
        int ex = s[t] - pair;                 // exclusive pair prefix
        if (2 * t < NB1) bsums[2 * t] = ex;
        if (2 * t + 1 < NB1) bsums[2 * t + 1] = ex + v0;
        if (t == 255) bsums[NB1] = s[255];    // total padded edge count
    }
    __threadfence();
    grid.sync();

    // ---- P4: scan3 (add block prefix; node i's block is i/256 = blockIdx) ----
    if (gtid < N_NODES) off[gtid] = off[gtid] + bsums[blockIdx.x];
    if (gtid == 0) off[N_NODES] = bsums[NB1];
    __threadfence();
    grid.sync();

    // ---- P5: scatter ----
    for (int e = gtid; e < N_EDGES; e += GT) {
        int sv = is32 ? ei[e] : ei[2 * e];
        int d = is32 ? ei[N_EDGES + e] : ei[2 * (N_EDGES + e)];
        srcs[off[d] + rank[e]] = sv;
    }
}

// ------- aggregation: one lane-group owns a full row; 4 edges in flight per node -------
// agg1: 8 nodes/wave x 8 lanes x 16B (full 128B row per group). Pad x4 => maskless.
__global__ void agg1_kernel(const ushort_t* __restrict__ xb, const int* __restrict__ off,
                            const int* __restrict__ srcs, ushort_t* __restrict__ aggb) {
    int wid = (blockIdx.x * 256 + threadIdx.x) >> 6;   // wave id
    int lane = threadIdx.x & 63;
    int n = lane >> 3;                       // node sub 0..7
    unsigned c = lane & 7;                   // 16B chunk of the 128B row
    int node = wid * 8 + n;                  // exact: 100000 = 8 * 12500 waves
    int b = off[node], e = off[node + 1];
    float acc[8];
#pragma unroll
    for (int j = 0; j < 8; j++) acc[j] = 0.f;
    const uint4* rows = (const uint4*)xb;    // 8 chunks per row (incl. zero row N)
    for (int p = b; p < e; p += 4) {
        int4 s = *(const int4*)(srcs + p);   // p is 4-aligned (pad x4), srcs base 256B-aligned
        uint4 A = rows[(unsigned)s.x * 8u + c];
        uint4 B = rows[(unsigned)s.y * 8u + c];
        uint4 C = rows[(unsigned)s.z * 8u + c];
        uint4 D = rows[(unsigned)s.w * 8u + c];
        upadd(acc, A);
        upadd(acc, B);
        upadd(acc, C);
        upadd(acc, D);
    }
    uint4 o = {(unsigned)f2bf(acc[0]) | ((unsigned)f2bf(acc[1]) << 16),
               (unsigned)f2bf(acc[2]) | ((unsigned)f2bf(acc[3]) << 16),
               (unsigned)f2bf(acc[4]) | ((unsigned)f2bf(acc[5]) << 16),
               (unsigned)f2bf(acc[6]) | ((unsigned)f2bf(acc[7]) << 16)};
    ((uint4*)(aggb + (size_t)node * FIN))[c] = o;   // 8 lanes = full row
}

// agg2: 4 nodes/wave x 16 lanes x 16B (full 256B row per group). Pad x4 => maskless.
__global__ void agg2_kernel(const ushort_t* __restrict__ h1b, const int* __restrict__ off,
                            const int* __restrict__ srcs, ushort_t* __restrict__ aggb) {
    int wid = (blockIdx.x * 256 + threadIdx.x) >> 6;   // wave id
    int lane = threadIdx.x & 63;
    int n = lane >> 4;                       // node sub 0..3
    unsigned c = lane & 15;                  // 16B chunk of the 256B row
    int node = wid * 4 + n;                  // exact: 100000 = 4 * 25000 waves
    int b = off[node], e = off[node + 1];
    float acc[8];
#pragma unroll
    for (int j = 0; j < 8; j++) acc[j] = 0.f;
    const uint4* rows = (const uint4*)h1b;   // 16 chunks per row (incl. zero row N)
    for (int p = b; p < e; p += 4) {
        int4 s = *(const int4*)(srcs + p);   // p is 4-aligned (pad x4), srcs base 256B-aligned
        uint4 A = rows[(unsigned)s.x * 16u + c];
        uint4 B = rows[(unsigned)s.y * 16u + c];
        uint4 C = rows[(unsigned)s.z * 16u + c];
        uint4 D = rows[(unsigned)s.w * 16u + c];
        upadd(acc, A);
        upadd(acc, B);
        upadd(acc, C);
        upadd(acc, D);
    }
    uint4 o = {(unsigned)f2bf(acc[0]) | ((unsigned)f2bf(acc[1]) << 16),
               (unsigned)f2bf(acc[2]) | ((unsigned)f2bf(acc[3]) << 16),
               (unsigned)f2bf(acc[4]) | ((unsigned)f2bf(acc[5]) << 16),
               (unsigned)f2bf(acc[6]) | ((unsigned)f2bf(acc[7]) << 16)};
    ((uint4*)(aggb + (size_t)node * HID))[c] = o;   // 16 lanes = full row
}

// ------- MFMA GEMM layer 1: h1 = elu([agg1,x] @ Wb1^T + b1) -------
__global__ __launch_bounds__(256) void g1_kernel(
    const ushort_t* __restrict__ aggb, const ushort_t* __restrict__ xb,
    const ushort_t* __restrict__ Wb1, const float* __restrict__ b1,
    ushort_t* __restrict__ h1b) {
    __shared__ short8 wl8[2048];                 // 32 KB
    ushort_t* wl = (ushort_t*)wl8;
#pragma unroll
    for (int it = 0; it < 8; it++) {
        int q = it * 256 + threadIdx.x;
        int n = q >> 4, c = q & 15;
        short8 v = ((const short8*)Wb1)[q];
        *(short8*)(wl + n * HID + ((c ^ (n & 7)) << 3)) = v;
    }
    __syncthreads();

    int wave = threadIdx.x >> 6;
    int lane = threadIdx.x & 63;
    int nb = blockIdx.x * 128 + wave * 32;
    if (nb >= N_NODES) return;   // after the only barrier
    int half = lane >> 5, col = lane & 31;
    int nA = nb + col;
    if (nA >= N_NODES) nA = N_NODES - 1;

    short8 areg[8];
#pragma unroll
    for (int s = 0; s < 4; s++)
        areg[s] = *(const short8*)(aggb + (size_t)nA * FIN + s * 16 + half * 8);
#pragma unroll
    for (int s = 4; s < 8; s++)
        areg[s] = *(const short8*)(xb + (size_t)nA * FIN + (s - 4) * 16 + half * 8);

    fx16 acc[4];
#pragma unroll
    for (int jt = 0; jt < 4; jt++)
#pragma unroll
        for (int r = 0; r < 16; r++) acc[jt][r] = 0.f;

#pragma unroll
    for (int s = 0; s < 8; s++) {
        int c = 2 * s + half;
#pragma unroll
        for (int jt = 0; jt < 4; jt++) {
            int n = jt * 32 + col;
            short8 bq = *(const short8*)(wl + n * HID + ((c ^ (n & 7)) << 3));
            acc[jt] = __builtin_amdgcn_mfma_f32_32x32x16_bf16(areg[s], bq, acc[jt], 0, 0, 0);
        }
    }
#pragma unroll
    for (int jt = 0; jt < 4; jt++) {
        int j = jt * 32 + col;
        float bias = b1[j];
#pragma unroll
        for (int r = 0; r < 16; r++) {
            int node = nb + (r & 3) + 8 * (r >> 2) + 4 * half;
            if (node < N_NODES) {
                float v = acc[jt][r] + bias;
                v = v > 0.f ? v : __expf(v) - 1.f;
                h1b[(size_t)node * HID + j] = f2bf(v);
            }
        }
    }
}

// ------- MFMA GEMM layer 2 + MFMA MLP head -------
// LDS (43008 B, 3 blocks/CU):
//   [0..32768)      Wb2 K-half staging (32 KB, two passes), later t2 tile
//   [0..34816)      t2 tile [node][feature], stride 136 ushorts (16B-aligned rows)
//   [34816..43008)  Wfc1 padded 32x128 bf16, XOR-swizzled (disjoint from Wb2 region)
// Head: fc1 as 8 MFMAs on the tile, relu*Wfc2 per lane, 5-round shfl_xor butterfly.
__global__ __launch_bounds__(256) void g2h_kernel(
    const ushort_t* __restrict__ agg2b, const ushort_t* __restrict__ h1b,
    const ushort_t* __restrict__ Wb2, const float* __restrict__ b2,
    const float* __restrict__ Wfc1, const float* __restrict__ bfc1,
    const float* __restrict__ Wfc2, const float* __restrict__ bfc2,
    float* __restrict__ out) {
    __shared__ ushort_t smem[21504];             // 43008 B
    ushort_t* wl = smem;                         // 16384 ushorts (32 KB)
    ushort_t* wf = smem + 17408;                 // 4096 ushorts (8 KB)

    // stage Wfc1b once (region never touched by Wb2/tile)
#pragma unroll
    for (int it = 0; it < 16; it++) {
        int idx = it * 256 + threadIdx.x;        // 0..4095
        int m = idx >> 7, k = idx & 127;
        float v = (m < 20) ? Wfc1[m * HID + k] : 0.f;
        wf[m * 128 + (((k >> 3) ^ (m & 7)) << 3) + (k & 7)] = f2bf(v);
    }
    // stage Wb2 K-half 0 (cols 0..127)
#pragma unroll
    for (int it = 0; it < 8; it++) {
        int q = it * 256 + threadIdx.x;          // 0..2047
        int n = q >> 4, c = q & 15;
        short8 v = *(const short8*)(Wb2 + (size_t)n * 256 + c * 8);
        *(short8*)(wl + n * 128 + ((c ^ (n & 7)) << 3)) = v;
    }

    int wave = threadIdx.x >> 6;
    int lane = threadIdx.x & 63;
    int half = lane >> 5, col = lane & 31;
    int nb = blockIdx.x * 128 + wave * 32;       // tail waves keep running (barriers!)
    int nA = nb + col;
    if (nA >= N_NODES) nA = N_NODES - 1;

    short8 areg[16];
#pragma unroll
    for (int s = 0; s < 8; s++)
        areg[s] = *(const short8*)(agg2b + (size_t)nA * HID + s * 16 + half * 8);
#pragma unroll
    for (int s = 8; s < 16; s++)
        areg[s] = *(const short8*)(h1b + (size_t)nA * HID + (s - 8) * 16 + half * 8);

    fx16 acc[4];
#pragma unroll
    for (int jt = 0; jt < 4; jt++)
#pragma unroll
        for (int r = 0; r < 16; r++) acc[jt][r] = 0.f;

    __syncthreads();
#pragma unroll
    for (int s = 0; s < 8; s++) {                // K 0..127 (agg2 part)
        int c = 2 * s + half;
#pragma unroll
        for (int jt = 0; jt < 4; jt++) {
            int n = jt * 32 + col;
            short8 bq = *(const short8*)(wl + n * 128 + ((c ^ (n & 7)) << 3));
            acc[jt] = __builtin_amdgcn_mfma_f32_32x32x16_bf16(areg[s], bq, acc[jt], 0, 0, 0);
        }
    }
    __syncthreads();
    // stage Wb2 K-half 1 (cols 128..255)
#pragma unroll
    for (int it = 0; it < 8; it++) {
        int q = it * 256 + threadIdx.x;
        int n = q >> 4, c = q & 15;
        short8 v = *(const short8*)(Wb2 + (size_t)n * 256 + 128 + c * 8);
        *(short8*)(wl + n * 128 + ((c ^ (n & 7)) << 3)) = v;
    }
    __syncthreads();
#pragma unroll
    for (int s = 8; s < 16; s++) {               // K 128..255 (h1 part)
        int c = 2 * (s - 8) + half;
#pragma unroll
        for (int jt = 0; jt < 4; jt++) {
            int n = jt * 32 + col;
            short8 bq = *(const short8*)(wl + n * 128 + ((c ^ (n & 7)) << 3));
            acc[jt] = __builtin_amdgcn_mfma_f32_32x32x16_bf16(areg[s], bq, acc[jt], 0, 0, 0);
        }
    }
    __syncthreads();   // weights dead; reuse [0..34816) as t2 tile

    // t2 tile [node_local][feature], stride 136 ushorts
    ushort_t* tl = smem;
#pragma unroll
    for (int jt = 0; jt < 4; jt++) {
        int j = jt * 32 + col;
        float bias = b2[j];
#pragma unroll
        for (int r = 0; r < 16; r++) {
            int nl = wave * 32 + (r & 3) + 8 * (r >> 2) + 4 * half;
            tl[nl * 136 + j] = f2bf(acc[jt][r] + bias);
        }
    }
    __syncthreads();

    // fc1 as MFMA: A = t2 tile rows (node m = wave*32+col), B = Wfc1b (row col)
    short8 af[8];
#pragma unroll
    for (int s = 0; s < 8; s++)
        af[s] = *(const short8*)(tl + (wave * 32 + col) * 136 + s * 16 + half * 8);
    fx16 fa;
#pragma unroll
    for (int r = 0; r < 16; r++) fa[r] = 0.f;
#pragma unroll
    for (int s = 0; s < 8; s++) {
        int c = 2 * s + half;
        short8 bw = *(const short8*)(wf + col * 128 + ((c ^ (col & 7)) << 3));
        fa = __builtin_amdgcn_mfma_f32_32x32x16_bf16(af[s], bw, fa, 0, 0, 0);
    }
    // epilogue: relu(+bfc1) * Wfc2, butterfly-sum over the 32 output cols
    float biasv = (col < 20) ? bfc1[col] : 0.f;
    float w2v = (col < 20) ? Wfc2[col] : 0.f;
    float bz = bfc2[0];
    float red[16];
#pragma unroll
    for (int r = 0; r < 16; r++) {
        float v = fa[r] + biasv;
        v = (v > 0.f ? v : 0.f) * w2v;
        v += __shfl_xor(v, 1);
        v += __shfl_xor(v, 2);
        v += __shfl_xor(v, 4);
        v += __shfl_xor(v, 8);
        v += __shfl_xor(v, 16);
        red[r] = v;
    }
    if (col == 0) {
#pragma unroll
        for (int r = 0; r < 16; r++) {
            int nl = wave * 32 + (r & 3) + 8 * (r >> 2) + 4 * half;
            int ng = blockIdx.x * 128 + nl;
            if (ng < N_NODES) out[ng] = red[r] + bz;
        }
    }
}

// ---------------- launch ----------------
extern "C" void kernel_launch(void* const* d_in, const int* in_sizes, int n_in,
                              void* d_out, int out_size, void* d_ws, size_t ws_size,
                              hipStream_t stream) {
    const int* ei = (const int*)d_in[1];
    const float* x = (const float*)d_in[0];
    const float* W1rel = (const float*)d_in[2];
    const float* b1 = (const float*)d_in[3];
    const float* W1root = (const float*)d_in[4];
    const float* W2rel = (const float*)d_in[5];
    const float* b2 = (const float*)d_in[6];
    const float* W2root = (const float*)d_in[7];
    const float* Wfc1 = (const float*)d_in[8];
    const float* bfc1 = (const float*)d_in[9];
    const float* Wfc2 = (const float*)d_in[10];
    const float* bfc2 = (const float*)d_in[11];
    float* out = (float*)d_out;

    // all offsets rounded to 256B so every buffer alignment is by construction
    char* ws = (char*)d_ws;
    size_t o = 0;
    auto alloc = [&](size_t bytes) {
        char* p = ws + o;
        o += (bytes + 255) & ~(size_t)255;
        return p;
    };
    int* deg = (int*)alloc((size_t)N_NODES * 4);
    int* off = (int*)alloc((size_t)(N_NODES + 1) * 4);
    int* bsums = (int*)alloc(4096);
    int* flag = (int*)alloc(256);
    int* rank = (int*)alloc((size_t)N_EDGES * 4);                    // 3.2 MB
    int* srcs = (int*)alloc((size_t)SRCS_CAP * 4);                   // 4.4 MB
    ushort_t* xb = (ushort_t*)alloc((size_t)(N_NODES + 1) * FIN * 2);   // 12.8 MB (+zero row)
    ushort_t* agg1b = (ushort_t*)alloc((size_t)N_NODES * FIN * 2);      // 12.8 MB
    ushort_t* h1b = (ushort_t*)alloc((size_t)(N_NODES + 1) * HID * 2);  // 25.6 MB (+zero row)
    ushort_t* agg2b = (ushort_t*)alloc((size_t)N_NODES * HID * 2);      // 25.6 MB
    ushort_t* Wb1 = (ushort_t*)alloc((size_t)HID * HID * 2);            // 32 KB
    ushort_t* Wb2 = (ushort_t*)alloc((size_t)HID * 2 * HID * 2);        // 64 KB

    const int GW = (N_NODES + 127) / 128;  // 782 blocks: 4 waves x 32 nodes
    const int GA1 = N_NODES / 32;          // 3125 blocks: 4 waves x 8 nodes
    const int GA2 = N_NODES / 16;          // 6250 blocks: 4 waves x 4 nodes

    void* args[] = {(void*)&ei, (void*)&x, (void*)&W1rel, (void*)&W1root,
                    (void*)&W2rel, (void*)&W2root,
                    (void*)&deg, (void*)&flag, (void*)&srcs, (void*)&rank,
                    (void*)&off, (void*)&bsums,
                    (void*)&xb, (void*)&h1b, (void*)&Wb1, (void*)&Wb2};
    hipLaunchCooperativeKernel((void*)csr_kernel, dim3(NB1), dim3(256), args, 0, stream);
    agg1_kernel<<<GA1, 256, 0, stream>>>(xb, off, srcs, agg1b);
    g1_kernel<<<GW, 256, 0, stream>>>(agg1b, xb, Wb1, b1, h1b);
    agg2_kernel<<<GA2, 256, 0, stream>>>(h1b, off, srcs, agg2b);
    g2h_kernel<<<GW, 256, 0, stream>>>(agg2b, h1b, Wb2, b2, Wfc1, bfc1, Wfc2, bfc2, out);
}

// Round 12
// 249.837 us; speedup vs baseline: 2.6179x; 2.6179x over previous
//
#include <hip/hip_runtime.h>

#define N_NODES 100000
#define N_EDGES 800000
#define FIN 64
#define HID 128
#define NB1 391   // ceil(N_NODES/256)
#define SRCS_CAP (N_EDGES + 3 * N_NODES)   // padded CSR capacity (pad to multiple of 4 per node)
#define GI (1024 * 256)                    // init_kernel grid threads

typedef unsigned short ushort_t;
typedef __attribute__((ext_vector_type(8))) short short8;   // 8 bf16 = 4 VGPRs (MFMA A/B frag)
typedef __attribute__((ext_vector_type(16))) float fx16;    // 32x32 MFMA C/D frag
typedef __attribute__((ext_vector_type(4))) unsigned short us4;

__device__ inline ushort_t f2bf(float f) {   // RNE fp32 -> bf16
    unsigned u = __float_as_uint(f);
    u += 0x7fffu + ((u >> 16) & 1u);
    return (ushort_t)(u >> 16);
}

__device__ inline void upadd(float* acc, uint4 A) {   // accumulate 8 bf16 of a 16B chunk
    acc[0] += __uint_as_float(A.x << 16);
    acc[1] += __uint_as_float(A.x & 0xffff0000u);
    acc[2] += __uint_as_float(A.y << 16);
    acc[3] += __uint_as_float(A.y & 0xffff0000u);
    acc[4] += __uint_as_float(A.z << 16);
    acc[5] += __uint_as_float(A.z & 0xffff0000u);
    acc[6] += __uint_as_float(A.w << 16);
    acc[7] += __uint_as_float(A.w & 0xffff0000u);
}

// ------- init: zero deg + sentinel srcs + cvt x/weights/zero-rows + block0 detect -------
// Replaces 3 launches. Detect is the PROVEN device probe (block-0 tree reduction,
// plain store — no init race). Do NOT replace with in_sizes heuristics (r8/r9 aborts).
// No grid.sync anywhere: cooperative sync costs ~90us/sync on gfx950 (r11).
__global__ __launch_bounds__(256) void init_kernel(
    const int* __restrict__ ei, const float* __restrict__ x,
    const float* __restrict__ W1rel, const float* __restrict__ W1root,
    const float* __restrict__ W2rel, const float* __restrict__ W2root,
    int* __restrict__ deg, int* __restrict__ flag, int* __restrict__ srcs,
    ushort_t* __restrict__ xb, ushort_t* __restrict__ h1b,
    ushort_t* __restrict__ Wb1, ushort_t* __restrict__ Wb2) {
    __shared__ int s[256];
    int t = threadIdx.x;
    int gtid = blockIdx.x * 256 + t;

    if (gtid < N_NODES) deg[gtid] = 0;
    for (int k = gtid; k < SRCS_CAP; k += GI) srcs[k] = N_NODES;
    for (int i = gtid; i < N_NODES * FIN / 4; i += GI) {
        float4 v = ((const float4*)x)[i];
        us4 o = {f2bf(v.x), f2bf(v.y), f2bf(v.z), f2bf(v.w)};
        ((us4*)xb)[i] = o;
    }
    us4 z = {0, 0, 0, 0};
    if (gtid < 16) ((us4*)xb)[(size_t)N_NODES * 16 + gtid] = z;          // xb zero row
    if (gtid >= 16 && gtid < 48) ((us4*)h1b)[(size_t)N_NODES * 32 + (gtid - 16)] = z;  // h1b zero row
    if (gtid < HID * HID) {
        int n = gtid >> 7, k = gtid & 127;
        float v = (k < FIN) ? W1rel[n * FIN + k] : W1root[n * FIN + (k - FIN)];
        Wb1[gtid] = f2bf(v);
    }
    if (gtid < HID * 2 * HID) {
        int n = gtid >> 8, k = gtid & 255;
        float v = (k < HID) ? W2rel[n * HID + k] : W2root[n * HID + (k - HID)];
        Wb2[gtid] = f2bf(v);
    }
    if (blockIdx.x == 0) {           // int64 little-endian => odd words all 0
        int bad = 0;
        for (int i = t; i < 8192; i += 256) bad |= ei[2 * i + 1];
        s[t] = bad;
        __syncthreads();
        for (int d = 128; d > 0; d >>= 1) {
            if (t < d) s[t] |= s[t + d];
            __syncthreads();
        }
        if (t == 0) *flag = (s[0] != 0) ? 1 : 0;   // 1 => int32 layout
    }
}

// ---------------- CSR build (padded to multiple of 4 per node) ----------------
__global__ void hist_kernel(const int* __restrict__ w, const int* __restrict__ flag,
                            int* __restrict__ deg, int* __restrict__ rank) {
    int e = blockIdx.x * 256 + threadIdx.x;
    if (e >= N_EDGES) return;
    int is32 = *flag;
    int d = is32 ? w[N_EDGES + e] : w[2 * (N_EDGES + e)];
    rank[e] = atomicAdd(&deg[d], 1);
}

__global__ void scan1_kernel(const int* __restrict__ deg, int* __restrict__ off,
                             int* __restrict__ bsums) {
    __shared__ int s[256];
    int t = threadIdx.x;
    int i = blockIdx.x * 256 + t;
    int v = (i < N_NODES) ? ((deg[i] + 3) & ~3) : 0;   // padded degree (x4)
    s[t] = v;
    __syncthreads();
    for (int d = 1; d < 256; d <<= 1) {
        int w = (t >= d) ? s[t - d] : 0;
        __syncthreads();
        s[t] += w;
        __syncthreads();
    }
    if (i < N_NODES) off[i] = s[t] - v;
    if (t == 255) bsums[blockIdx.x] = s[255];
}

// scan2+scan3 merged: block b re-derives its prefix by summing bsums[0..b).
// 391 ints per block — trivial vs a launch gap.
__global__ void scan23_kernel(int* __restrict__ off, const int* __restrict__ bsums) {
    __shared__ int s[256];
    int t = threadIdx.x, b = blockIdx.x;
    int pre = 0, tot = 0;
    for (int j = t; j < NB1; j += 256) {
        int v = bsums[j];
        if (j < b) pre += v;
        tot += v;
    }
    s[t] = pre;
    __syncthreads();
    for (int d = 128; d > 0; d >>= 1) {
        if (t < d) s[t] += s[t + d];
        __syncthreads();
    }
    int prefix = s[0];
    __syncthreads();
    int i = b * 256 + t;
    if (i < N_NODES) off[i] += prefix;
    if (b == 0) {
        s[t] = tot;
        __syncthreads();
        for (int d = 128; d > 0; d >>= 1) {
            if (t < d) s[t] += s[t + d];
            __syncthreads();
        }
        if (t == 0) off[N_NODES] = s[0];   // total padded edge count
    }
}

__global__ void scatter_kernel(const int* __restrict__ w, const int* __restrict__ flag,
                               const int* __restrict__ off, const int* __restrict__ rank,
                               int* __restrict__ srcs) {
    int e = blockIdx.x * 256 + threadIdx.x;
    if (e >= N_EDGES) return;
    int is32 = *flag;
    int s = is32 ? w[e] : w[2 * e];
    int d = is32 ? w[N_EDGES + e] : w[2 * (N_EDGES + e)];
    srcs[off[d] + rank[e]] = s;
}

// ------- aggregation: one lane-group owns a full row; 4 edges in flight per node -------
// agg1: 8 nodes/wave x 8 lanes x 16B (full 128B row per group). Pad x4 => maskless.
__global__ void agg1_kernel(const ushort_t* __restrict__ xb, const int* __restrict__ off,
                            const int* __restrict__ srcs, ushort_t* __restrict__ aggb) {
    int wid = (blockIdx.x * 256 + threadIdx.x) >> 6;   // wave id
    int lane = threadIdx.x & 63;
    int n = lane >> 3;                       // node sub 0..7
    unsigned c = lane & 7;                   // 16B chunk of the 128B row
    int node = wid * 8 + n;                  // exact: 100000 = 8 * 12500 waves
    int b = off[node], e = off[node + 1];
    float acc[8];
#pragma unroll
    for (int j = 0; j < 8; j++) acc[j] = 0.f;
    const uint4* rows = (const uint4*)xb;    // 8 chunks per row (incl. zero row N)
    for (int p = b; p < e; p += 4) {
        int4 s = *(const int4*)(srcs + p);   // p is 4-aligned (pad x4), srcs base 256B-aligned
        uint4 A = rows[(unsigned)s.x * 8u + c];
        uint4 B = rows[(unsigned)s.y * 8u + c];
        uint4 C = rows[(unsigned)s.z * 8u + c];
        uint4 D = rows[(unsigned)s.w * 8u + c];
        upadd(acc, A);
        upadd(acc, B);
        upadd(acc, C);
        upadd(acc, D);
    }
    uint4 o = {(unsigned)f2bf(acc[0]) | ((unsigned)f2bf(acc[1]) << 16),
               (unsigned)f2bf(acc[2]) | ((unsigned)f2bf(acc[3]) << 16),
               (unsigned)f2bf(acc[4]) | ((unsigned)f2bf(acc[5]) << 16),
               (unsigned)f2bf(acc[6]) | ((unsigned)f2bf(acc[7]) << 16)};
    ((uint4*)(aggb + (size_t)node * FIN))[c] = o;   // 8 lanes = full row
}

// agg2: 4 nodes/wave x 16 lanes x 16B (full 256B row per group). Pad x4 => maskless.
__global__ void agg2_kernel(const ushort_t* __restrict__ h1b, const int* __restrict__ off,
                            const int* __restrict__ srcs, ushort_t* __restrict__ aggb) {
    int wid = (blockIdx.x * 256 + threadIdx.x) >> 6;   // wave id
    int lane = threadIdx.x & 63;
    int n = lane >> 4;                       // node sub 0..3
    unsigned c = lane & 15;                  // 16B chunk of the 256B row
    int node = wid * 4 + n;                  // exact: 100000 = 4 * 25000 waves
    int b = off[node], e = off[node + 1];
    float acc[8];
#pragma unroll
    for (int j = 0; j < 8; j++) acc[j] = 0.f;
    const uint4* rows = (const uint4*)h1b;   // 16 chunks per row (incl. zero row N)
    for (int p = b; p < e; p += 4) {
        int4 s = *(const int4*)(srcs + p);   // p is 4-aligned (pad x4), srcs base 256B-aligned
        uint4 A = rows[(unsigned)s.x * 16u + c];
        uint4 B = rows[(unsigned)s.y * 16u + c];
        uint4 C = rows[(unsigned)s.z * 16u + c];
        uint4 D = rows[(unsigned)s.w * 16u + c];
        upadd(acc, A);
        upadd(acc, B);
        upadd(acc, C);
        upadd(acc, D);
    }
    uint4 o = {(unsigned)f2bf(acc[0]) | ((unsigned)f2bf(acc[1]) << 16),
               (unsigned)f2bf(acc[2]) | ((unsigned)f2bf(acc[3]) << 16),
               (unsigned)f2bf(acc[4]) | ((unsigned)f2bf(acc[5]) << 16),
               (unsigned)f2bf(acc[6]) | ((unsigned)f2bf(acc[7]) << 16)};
    ((uint4*)(aggb + (size_t)node * HID))[c] = o;   // 16 lanes = full row
}

// ------- MFMA GEMM layer 1: h1 = elu([agg1,x] @ Wb1^T + b1) -------
__global__ __launch_bounds__(256) void g1_kernel(
    const ushort_t* __restrict__ aggb, const ushort_t* __restrict__ xb,
    const ushort_t* __restrict__ Wb1, const float* __restrict__ b1,
    ushort_t* __restrict__ h1b) {
    __shared__ short8 wl8[2048];                 // 32 KB
    ushort_t* wl = (ushort_t*)wl8;
#pragma unroll
    for (int it = 0; it < 8; it++) {
        int q = it * 256 + threadIdx.x;
        int n = q >> 4, c = q & 15;
        short8 v = ((const short8*)Wb1)[q];
        *(short8*)(wl + n * HID + ((c ^ (n & 7)) << 3)) = v;
    }
    __syncthreads();

    int wave = threadIdx.x >> 6;
    int lane = threadIdx.x & 63;
    int nb = blockIdx.x * 128 + wave * 32;
    if (nb >= N_NODES) return;   // after the only barrier
    int half = lane >> 5, col = lane & 31;
    int nA = nb + col;
    if (nA >= N_NODES) nA = N_NODES - 1;

    short8 areg[8];
#pragma unroll
    for (int s = 0; s < 4; s++)
        areg[s] = *(const short8*)(aggb + (size_t)nA * FIN + s * 16 + half * 8);
#pragma unroll
    for (int s = 4; s < 8; s++)
        areg[s] = *(const short8*)(xb + (size_t)nA * FIN + (s - 4) * 16 + half * 8);

    fx16 acc[4];
#pragma unroll
    for (int jt = 0; jt < 4; jt++)
#pragma unroll
        for (int r = 0; r < 16; r++) acc[jt][r] = 0.f;

#pragma unroll
    for (int s = 0; s < 8; s++) {
        int c = 2 * s + half;
#pragma unroll
        for (int jt = 0; jt < 4; jt++) {
            int n = jt * 32 + col;
            short8 bq = *(const short8*)(wl + n * HID + ((c ^ (n & 7)) << 3));
            acc[jt] = __builtin_amdgcn_mfma_f32_32x32x16_bf16(areg[s], bq, acc[jt], 0, 0, 0);
        }
    }
#pragma unroll
    for (int jt = 0; jt < 4; jt++) {
        int j = jt * 32 + col;
        float bias = b1[j];
#pragma unroll
        for (int r = 0; r < 16; r++) {
            int node = nb + (r & 3) + 8 * (r >> 2) + 4 * half;
            if (node < N_NODES) {
                float v = acc[jt][r] + bias;
                v = v > 0.f ? v : __expf(v) - 1.f;
                h1b[(size_t)node * HID + j] = f2bf(v);
            }
        }
    }
}

// ------- MFMA GEMM layer 2 + MFMA MLP head -------
// LDS (43008 B, 3 blocks/CU):
//   [0..32768)      Wb2 K-half staging (32 KB, two passes), later t2 tile
//   [0..34816)      t2 tile [node][feature], stride 136 ushorts (16B-aligned rows)
//   [34816..43008)  Wfc1 padded 32x128 bf16, XOR-swizzled (disjoint from Wb2 region)
// Head: fc1 as 8 MFMAs on the tile, relu*Wfc2 per lane, 5-round shfl_xor butterfly.
__global__ __launch_bounds__(256) void g2h_kernel(
    const ushort_t* __restrict__ agg2b, const ushort_t* __restrict__ h1b,
    const ushort_t* __restrict__ Wb2, const float* __restrict__ b2,
    const float* __restrict__ Wfc1, const float* __restrict__ bfc1,
    const float* __restrict__ Wfc2, const float* __restrict__ bfc2,
    float* __restrict__ out) {
    __shared__ ushort_t smem[21504];             // 43008 B
    ushort_t* wl = smem;                         // 16384 ushorts (32 KB)
    ushort_t* wf = smem + 17408;                 // 4096 ushorts (8 KB)

    // stage Wfc1b once (region never touched by Wb2/tile)
#pragma unroll
    for (int it = 0; it < 16; it++) {
        int idx = it * 256 + threadIdx.x;        // 0..4095
        int m = idx >> 7, k = idx & 127;
        float v = (m < 20) ? Wfc1[m * HID + k] : 0.f;
        wf[m * 128 + (((k >> 3) ^ (m & 7)) << 3) + (k & 7)] = f2bf(v);
    }
    // stage Wb2 K-half 0 (cols 0..127)
#pragma unroll
    for (int it = 0; it < 8; it++) {
        int q = it * 256 + threadIdx.x;          // 0..2047
        int n = q >> 4, c = q & 15;
        short8 v = *(const short8*)(Wb2 + (size_t)n * 256 + c * 8);
        *(short8*)(wl + n * 128 + ((c ^ (n & 7)) << 3)) = v;
    }

    int wave = threadIdx.x >> 6;
    int lane = threadIdx.x & 63;
    int half = lane >> 5, col = lane & 31;
    int nb = blockIdx.x * 128 + wave * 32;       // tail waves keep running (barriers!)
    int nA = nb + col;
    if (nA >= N_NODES) nA = N_NODES - 1;

    short8 areg[16];
#pragma unroll
    for (int s = 0; s < 8; s++)
        areg[s] = *(const short8*)(agg2b + (size_t)nA * HID + s * 16 + half * 8);
#pragma unroll
    for (int s = 8; s < 16; s++)
        areg[s] = *(const short8*)(h1b + (size_t)nA * HID + (s - 8) * 16 + half * 8);

    fx16 acc[4];
#pragma unroll
    for (int jt = 0; jt < 4; jt++)
#pragma unroll
        for (int r = 0; r < 16; r++) acc[jt][r] = 0.f;

    __syncthreads();
#pragma unroll
    for (int s = 0; s < 8; s++) {                // K 0..127 (agg2 part)
        int c = 2 * s + half;
#pragma unroll
        for (int jt = 0; jt < 4; jt++) {
            int n = jt * 32 + col;
            short8 bq = *(const short8*)(wl + n * 128 + ((c ^ (n & 7)) << 3));
            acc[jt] = __builtin_amdgcn_mfma_f32_32x32x16_bf16(areg[s], bq, acc[jt], 0, 0, 0);
        }
    }
    __syncthreads();
    // stage Wb2 K-half 1 (cols 128..255)
#pragma unroll
    for (int it = 0; it < 8; it++) {
        int q = it * 256 + threadIdx.x;
        int n = q >> 4, c = q & 15;
        short8 v = *(const short8*)(Wb2 + (size_t)n * 256 + 128 + c * 8);
        *(short8*)(wl + n * 128 + ((c ^ (n & 7)) << 3)) = v;
    }
    __syncthreads();
#pragma unroll
    for (int s = 8; s < 16; s++) {               // K 128..255 (h1 part)
        int c = 2 * (s - 8) + half;
#pragma unroll
        for (int jt = 0; jt < 4; jt++) {
            int n = jt * 32 + col;
            short8 bq = *(const short8*)(wl + n * 128 + ((c ^ (n & 7)) << 3));
            acc[jt] = __builtin_amdgcn_mfma_f32_32x32x16_bf16(areg[s], bq, acc[jt], 0, 0, 0);
        }
    }
    __syncthreads();   // weights dead; reuse [0..34816) as t2 tile

    // t2 tile [node_local][feature], stride 136 ushorts
    ushort_t* tl = smem;
#pragma unroll
    for (int jt = 0; jt < 4; jt++) {
        int j = jt * 32 + col;
        float bias = b2[j];
#pragma unroll
        for (int r = 0; r < 16; r++) {
            int nl = wave * 32 + (r & 3) + 8 * (r >> 2) + 4 * half;
            tl[nl * 136 + j] = f2bf(acc[jt][r] + bias);
        }
    }
    __syncthreads();

    // fc1 as MFMA: A = t2 tile rows (node m = wave*32+col), B = Wfc1b (row col)
    short8 af[8];
#pragma unroll
    for (int s = 0; s < 8; s++)
        af[s] = *(const short8*)(tl + (wave * 32 + col) * 136 + s * 16 + half * 8);
    fx16 fa;
#pragma unroll
    for (int r = 0; r < 16; r++) fa[r] = 0.f;
#pragma unroll
    for (int s = 0; s < 8; s++) {
        int c = 2 * s + half;
        short8 bw = *(const short8*)(wf + col * 128 + ((c ^ (col & 7)) << 3));
        fa = __builtin_amdgcn_mfma_f32_32x32x16_bf16(af[s], bw, fa, 0, 0, 0);
    }
    // epilogue: relu(+bfc1) * Wfc2, butterfly-sum over the 32 output cols
    float biasv = (col < 20) ? bfc1[col] : 0.f;
    float w2v = (col < 20) ? Wfc2[col] : 0.f;
    float bz = bfc2[0];
    float red[16];
#pragma unroll
    for (int r = 0; r < 16; r++) {
        float v = fa[r] + biasv;
        v = (v > 0.f ? v : 0.f) * w2v;
        v += __shfl_xor(v, 1);
        v += __shfl_xor(v, 2);
        v += __shfl_xor(v, 4);
        v += __shfl_xor(v, 8);
        v += __shfl_xor(v, 16);
        red[r] = v;
    }
    if (col == 0) {
#pragma unroll
        for (int r = 0; r < 16; r++) {
            int nl = wave * 32 + (r & 3) + 8 * (r >> 2) + 4 * half;
            int ng = blockIdx.x * 128 + nl;
            if (ng < N_NODES) out[ng] = red[r] + bz;
        }
    }
}

// ---------------- launch ----------------
extern "C" void kernel_launch(void* const* d_in, const int* in_sizes, int n_in,
                              void* d_out, int out_size, void* d_ws, size_t ws_size,
                              hipStream_t stream) {
    const float* x = (const float*)d_in[0];
    const int* ei = (const int*)d_in[1];
    const float* W1rel = (const float*)d_in[2];
    const float* b1 = (const float*)d_in[3];
    const float* W1root = (const float*)d_in[4];
    const float* W2rel = (const float*)d_in[5];
    const float* b2 = (const float*)d_in[6];
    const float* W2root = (const float*)d_in[7];
    const float* Wfc1 = (const float*)d_in[8];
    const float* bfc1 = (const float*)d_in[9];
    const float* Wfc2 = (const float*)d_in[10];
    const float* bfc2 = (const float*)d_in[11];
    float* out = (float*)d_out;

    // all offsets rounded to 256B so every buffer alignment is by construction
    char* ws = (char*)d_ws;
    size_t o = 0;
    auto alloc = [&](size_t bytes) {
        char* p = ws + o;
        o += (bytes + 255) & ~(size_t)255;
        return p;
    };
    int* deg = (int*)alloc((size_t)N_NODES * 4);
    int* off = (int*)alloc((size_t)(N_NODES + 1) * 4);
    int* bsums = (int*)alloc(4096);
    int* flag = (int*)alloc(256);
    int* rank = (int*)alloc((size_t)N_EDGES * 4);                    // 3.2 MB
    int* srcs = (int*)alloc((size_t)SRCS_CAP * 4);                   // 4.4 MB
    ushort_t* xb = (ushort_t*)alloc((size_t)(N_NODES + 1) * FIN * 2);   // 12.8 MB (+zero row)
    ushort_t* agg1b = (ushort_t*)alloc((size_t)N_NODES * FIN * 2);      // 12.8 MB
    ushort_t* h1b = (ushort_t*)alloc((size_t)(N_NODES + 1) * HID * 2);  // 25.6 MB (+zero row)
    ushort_t* agg2b = (ushort_t*)alloc((size_t)N_NODES * HID * 2);      // 25.6 MB
    ushort_t* Wb1 = (ushort_t*)alloc((size_t)HID * HID * 2);            // 32 KB
    ushort_t* Wb2 = (ushort_t*)alloc((size_t)HID * 2 * HID * 2);        // 64 KB

    const int GW = (N_NODES + 127) / 128;  // 782 blocks: 4 waves x 32 nodes
    const int GA1 = N_NODES / 32;          // 3125 blocks: 4 waves x 8 nodes
    const int GA2 = N_NODES / 16;          // 6250 blocks: 4 waves x 4 nodes

    init_kernel<<<1024, 256, 0, stream>>>(ei, x, W1rel, W1root, W2rel, W2root,
                                          deg, flag, srcs, xb, h1b, Wb1, Wb2);
    hist_kernel<<<(N_EDGES + 255) / 256, 256, 0, stream>>>(ei, flag, deg, rank);
    scan1_kernel<<<NB1, 256, 0, stream>>>(deg, off, bsums);
    scan23_kernel<<<NB1, 256, 0, stream>>>(off, bsums);
    scatter_kernel<<<(N_EDGES + 255) / 256, 256, 0, stream>>>(ei, flag, off, rank, srcs);
    agg1_kernel<<<GA1, 256, 0, stream>>>(xb, off, srcs, agg1b);
    g1_kernel<<<GW, 256, 0, stream>>>(agg1b, xb, Wb1, b1, h1b);
    agg2_kernel<<<GA2, 256, 0, stream>>>(h1b, off, srcs, agg2b);
    g2h_kernel<<<GW, 256, 0, stream>>>(agg2b, h1b, Wb2, b2, Wfc1, bfc1, Wfc2, bfc2, out);
}

// Round 13
// 216.128 us; speedup vs baseline: 3.0262x; 1.1560x over previous
//
#include <hip/hip_runtime.h>

#define N_NODES 100000
#define N_EDGES 800000
#define FIN 64
#define HID 128
#define NB1 391   // ceil(N_NODES/256)
#define SRCS_CAP (N_EDGES + 3 * N_NODES)   // padded CSR capacity (pad to multiple of 4 per node)
#define GI (1024 * 256)                    // init_kernel grid threads

typedef unsigned short ushort_t;
typedef __attribute__((ext_vector_type(8))) short short8;   // 8 bf16 = 4 VGPRs (MFMA A/B frag)
typedef __attribute__((ext_vector_type(16))) float fx16;    // 32x32 MFMA C/D frag
typedef __attribute__((ext_vector_type(4))) unsigned short us4;

__device__ inline ushort_t f2bf(float f) {   // RNE fp32 -> bf16
    unsigned u = __float_as_uint(f);
    u += 0x7fffu + ((u >> 16) & 1u);
    return (ushort_t)(u >> 16);
}

__device__ inline void upadd(float* acc, uint4 A) {   // accumulate 8 bf16 of a 16B chunk
    acc[0] += __uint_as_float(A.x << 16);
    acc[1] += __uint_as_float(A.x & 0xffff0000u);
    acc[2] += __uint_as_float(A.y << 16);
    acc[3] += __uint_as_float(A.y & 0xffff0000u);
    acc[4] += __uint_as_float(A.z << 16);
    acc[5] += __uint_as_float(A.z & 0xffff0000u);
    acc[6] += __uint_as_float(A.w << 16);
    acc[7] += __uint_as_float(A.w & 0xffff0000u);
}

// ------- init: zero deg + sentinel srcs + cvt x/W1 + fused layer2 weights + detect -------
// Folded-weight algebra (layer2 has no activation before the head):
//   M1 = Wfc1@W2rel (20x128), M2 = Wfc1@W2root, cb = Wfc1@b2 + bfc1.
// Mb rows: [0..20) = M1, [20..32) = 0, [32..52) = M2, [52..64) = 0.
// Detect is the PROVEN device probe — do NOT replace with in_sizes heuristics (r8/r9).
__global__ __launch_bounds__(256) void init_kernel(
    const int* __restrict__ ei, const float* __restrict__ x,
    const float* __restrict__ W1rel, const float* __restrict__ W1root,
    const float* __restrict__ W2rel, const float* __restrict__ W2root,
    const float* __restrict__ b2, const float* __restrict__ Wfc1,
    const float* __restrict__ bfc1, const float* __restrict__ Wfc2,
    int* __restrict__ deg, int* __restrict__ flag, int* __restrict__ srcs,
    ushort_t* __restrict__ xb, ushort_t* __restrict__ Wb1,
    ushort_t* __restrict__ Mb, float* __restrict__ cbp, float* __restrict__ w2p) {
    __shared__ int s[256];
    int t = threadIdx.x;
    int gtid = blockIdx.x * 256 + t;

    if (gtid < N_NODES) deg[gtid] = 0;
    for (int k = gtid; k < SRCS_CAP; k += GI) srcs[k] = N_NODES;
    for (int i = gtid; i < N_NODES * FIN / 4; i += GI) {
        float4 v = ((const float4*)x)[i];
        us4 o = {f2bf(v.x), f2bf(v.y), f2bf(v.z), f2bf(v.w)};
        ((us4*)xb)[i] = o;
    }
    us4 z = {0, 0, 0, 0};
    if (gtid < 16) ((us4*)xb)[(size_t)N_NODES * 16 + gtid] = z;   // xb zero row
    if (gtid < HID * HID) {
        int n = gtid >> 7, k = gtid & 127;
        float v = (k < FIN) ? W1rel[n * FIN + k] : W1root[n * FIN + (k - FIN)];
        Wb1[gtid] = f2bf(v);
    }
    // fused layer2 weights: blocks 0..31 compute Mb (8192 outputs, 1/thread)
    if (blockIdx.x < 32) {
        int idx = blockIdx.x * 256 + t;     // 0..8191
        int n = idx >> 7, k = idx & 127;
        float acc = 0.f;
        if (n < 20) {
            for (int j = 0; j < HID; j++) acc += Wfc1[n * HID + j] * W2rel[j * HID + k];
        } else if (n >= 32 && n < 52) {
            int m = n - 32;
            for (int j = 0; j < HID; j++) acc += Wfc1[m * HID + j] * W2root[j * HID + k];
        }
        Mb[idx] = f2bf(acc);
    }
    if (blockIdx.x == 32 && t < 32) {
        float cv = 0.f, wv = 0.f;
        if (t < 20) {
            for (int j = 0; j < HID; j++) cv += Wfc1[t * HID + j] * b2[j];
            cv += bfc1[t];
            wv = Wfc2[t];
        }
        cbp[t] = cv;
        w2p[t] = wv;
    }
    if (blockIdx.x == 33) {          // int64 little-endian => odd words all 0
        int bad = 0;
        for (int i = t; i < 8192; i += 256) bad |= ei[2 * i + 1];
        s[t] = bad;
        __syncthreads();
        for (int d = 128; d > 0; d >>= 1) {
            if (t < d) s[t] |= s[t + d];
            __syncthreads();
        }
        if (t == 0) *flag = (s[0] != 0) ? 1 : 0;   // 1 => int32 layout
    }
}

// ---------------- CSR build (padded to multiple of 4 per node) ----------------
__global__ void hist_kernel(const int* __restrict__ w, const int* __restrict__ flag,
                            int* __restrict__ deg, int* __restrict__ rank) {
    int e = blockIdx.x * 256 + threadIdx.x;
    if (e >= N_EDGES) return;
    int is32 = *flag;
    int d = is32 ? w[N_EDGES + e] : w[2 * (N_EDGES + e)];
    rank[e] = atomicAdd(&deg[d], 1);
}

__global__ void scan1_kernel(const int* __restrict__ deg, int* __restrict__ off,
                             int* __restrict__ bsums) {
    __shared__ int s[256];
    int t = threadIdx.x;
    int i = blockIdx.x * 256 + t;
    int v = (i < N_NODES) ? ((deg[i] + 3) & ~3) : 0;   // padded degree (x4)
    s[t] = v;
    __syncthreads();
    for (int d = 1; d < 256; d <<= 1) {
        int w = (t >= d) ? s[t - d] : 0;
        __syncthreads();
        s[t] += w;
        __syncthreads();
    }
    if (i < N_NODES) off[i] = s[t] - v;
    if (t == 255) bsums[blockIdx.x] = s[255];
}

// scan2+scan3 merged: block b re-derives its prefix by summing bsums[0..b).
__global__ void scan23_kernel(int* __restrict__ off, const int* __restrict__ bsums) {
    __shared__ int s[256];
    int t = threadIdx.x, b = blockIdx.x;
    int pre = 0, tot = 0;
    for (int j = t; j < NB1; j += 256) {
        int v = bsums[j];
        if (j < b) pre += v;
        tot += v;
    }
    s[t] = pre;
    __syncthreads();
    for (int d = 128; d > 0; d >>= 1) {
        if (t < d) s[t] += s[t + d];
        __syncthreads();
    }
    int prefix = s[0];
    __syncthreads();
    int i = b * 256 + t;
    if (i < N_NODES) off[i] += prefix;
    if (b == 0) {
        s[t] = tot;
        __syncthreads();
        for (int d = 128; d > 0; d >>= 1) {
            if (t < d) s[t] += s[t + d];
            __syncthreads();
        }
        if (t == 0) off[N_NODES] = s[0];   // total padded edge count
    }
}

__global__ void scatter_kernel(const int* __restrict__ w, const int* __restrict__ flag,
                               const int* __restrict__ off, const int* __restrict__ rank,
                               int* __restrict__ srcs) {
    int e = blockIdx.x * 256 + threadIdx.x;
    if (e >= N_EDGES) return;
    int is32 = *flag;
    int s = is32 ? w[e] : w[2 * e];
    int d = is32 ? w[N_EDGES + e] : w[2 * (N_EDGES + e)];
    srcs[off[d] + rank[e]] = s;
}

// ------- agg1: 8 nodes/wave x 8 lanes x 16B (full 128B row). Pad x4 => maskless -------
__global__ void agg1_kernel(const ushort_t* __restrict__ xb, const int* __restrict__ off,
                            const int* __restrict__ srcs, ushort_t* __restrict__ aggb) {
    int wid = (blockIdx.x * 256 + threadIdx.x) >> 6;   // wave id
    int lane = threadIdx.x & 63;
    int n = lane >> 3;                       // node sub 0..7
    unsigned c = lane & 7;                   // 16B chunk of the 128B row
    int node = wid * 8 + n;                  // exact: 100000 = 8 * 12500 waves
    int b = off[node], e = off[node + 1];
    float acc[8];
#pragma unroll
    for (int j = 0; j < 8; j++) acc[j] = 0.f;
    const uint4* rows = (const uint4*)xb;    // 8 chunks per row (incl. zero row N)
    for (int p = b; p < e; p += 4) {
        int4 s = *(const int4*)(srcs + p);   // p is 4-aligned (pad x4), srcs base 256B-aligned
        uint4 A = rows[(unsigned)s.x * 8u + c];
        uint4 B = rows[(unsigned)s.y * 8u + c];
        uint4 C = rows[(unsigned)s.z * 8u + c];
        uint4 D = rows[(unsigned)s.w * 8u + c];
        upadd(acc, A);
        upadd(acc, B);
        upadd(acc, C);
        upadd(acc, D);
    }
    uint4 o = {(unsigned)f2bf(acc[0]) | ((unsigned)f2bf(acc[1]) << 16),
               (unsigned)f2bf(acc[2]) | ((unsigned)f2bf(acc[3]) << 16),
               (unsigned)f2bf(acc[4]) | ((unsigned)f2bf(acc[5]) << 16),
               (unsigned)f2bf(acc[6]) | ((unsigned)f2bf(acc[7]) << 16)};
    ((uint4*)(aggb + (size_t)node * FIN))[c] = o;   // 8 lanes = full row
}

// ------- MFMA GEMM layer 1: h1 = elu([agg1,x] @ Wb1^T + b1) -------
__global__ __launch_bounds__(256) void g1_kernel(
    const ushort_t* __restrict__ aggb, const ushort_t* __restrict__ xb,
    const ushort_t* __restrict__ Wb1, const float* __restrict__ b1,
    ushort_t* __restrict__ h1b) {
    __shared__ short8 wl8[2048];                 // 32 KB
    ushort_t* wl = (ushort_t*)wl8;
#pragma unroll
    for (int it = 0; it < 8; it++) {
        int q = it * 256 + threadIdx.x;
        int n = q >> 4, c = q & 15;
        short8 v = ((const short8*)Wb1)[q];
        *(short8*)(wl + n * HID + ((c ^ (n & 7)) << 3)) = v;
    }
    __syncthreads();

    int wave = threadIdx.x >> 6;
    int lane = threadIdx.x & 63;
    int nb = blockIdx.x * 128 + wave * 32;
    if (nb >= N_NODES) return;   // after the only barrier
    int half = lane >> 5, col = lane & 31;
    int nA = nb + col;
    if (nA >= N_NODES) nA = N_NODES - 1;

    short8 areg[8];
#pragma unroll
    for (int s = 0; s < 4; s++)
        areg[s] = *(const short8*)(aggb + (size_t)nA * FIN + s * 16 + half * 8);
#pragma unroll
    for (int s = 4; s < 8; s++)
        areg[s] = *(const short8*)(xb + (size_t)nA * FIN + (s - 4) * 16 + half * 8);

    fx16 acc[4];
#pragma unroll
    for (int jt = 0; jt < 4; jt++)
#pragma unroll
        for (int r = 0; r < 16; r++) acc[jt][r] = 0.f;

#pragma unroll
    for (int s = 0; s < 8; s++) {
        int c = 2 * s + half;
#pragma unroll
        for (int jt = 0; jt < 4; jt++) {
            int n = jt * 32 + col;
            short8 bq = *(const short8*)(wl + n * HID + ((c ^ (n & 7)) << 3));
            acc[jt] = __builtin_amdgcn_mfma_f32_32x32x16_bf16(areg[s], bq, acc[jt], 0, 0, 0);
        }
    }
#pragma unroll
    for (int jt = 0; jt < 4; jt++) {
        int j = jt * 32 + col;
        float bias = b1[j];
#pragma unroll
        for (int r = 0; r < 16; r++) {
            int node = nb + (r & 3) + 8 * (r >> 2) + 4 * half;
            if (node < N_NODES) {
                float v = acc[jt][r] + bias;
                v = v > 0.f ? v : __expf(v) - 1.f;
                h1b[(size_t)node * HID + j] = f2bf(v);
            }
        }
    }
}

// ------- MFMA GEMM: uv = h1 @ Mb^T (N x 64: cols 0..31 u-part, 32..63 v-part) -------
// No bias (b2/bfc1 folded into cbp). Also zero-fills the uvb sentinel row.
__global__ __launch_bounds__(256) void g2_kernel(
    const ushort_t* __restrict__ h1b, const ushort_t* __restrict__ Mb,
    ushort_t* __restrict__ uvb) {
    __shared__ short8 ml8[1024];                 // 16 KB: 64 rows x 128
    ushort_t* ml = (ushort_t*)ml8;
    us4 z = {0, 0, 0, 0};
    if (blockIdx.x == 0 && threadIdx.x < 8)      // uvb zero row (pad slots gather it)
        ((us4*)(uvb + (size_t)N_NODES * 64))[threadIdx.x] = z;
#pragma unroll
    for (int it = 0; it < 4; it++) {
        int q = it * 256 + threadIdx.x;          // 0..1023
        int n = q >> 4, c = q & 15;
        short8 v = ((const short8*)Mb)[q];
        *(short8*)(ml + n * HID + ((c ^ (n & 7)) << 3)) = v;
    }
    __syncthreads();

    int wave = threadIdx.x >> 6;
    int lane = threadIdx.x & 63;
    int nb = blockIdx.x * 128 + wave * 32;
    if (nb >= N_NODES) return;   // after the only barrier
    int half = lane >> 5, col = lane & 31;
    int nA = nb + col;
    if (nA >= N_NODES) nA = N_NODES - 1;

    short8 areg[8];
#pragma unroll
    for (int s = 0; s < 8; s++)
        areg[s] = *(const short8*)(h1b + (size_t)nA * HID + s * 16 + half * 8);

    fx16 acc[2];
#pragma unroll
    for (int jt = 0; jt < 2; jt++)
#pragma unroll
        for (int r = 0; r < 16; r++) acc[jt][r] = 0.f;

#pragma unroll
    for (int s = 0; s < 8; s++) {
        int c = 2 * s + half;
#pragma unroll
        for (int jt = 0; jt < 2; jt++) {
            int n = jt * 32 + col;
            short8 bq = *(const short8*)(ml + n * HID + ((c ^ (n & 7)) << 3));
            acc[jt] = __builtin_amdgcn_mfma_f32_32x32x16_bf16(areg[s], bq, acc[jt], 0, 0, 0);
        }
    }
#pragma unroll
    for (int jt = 0; jt < 2; jt++) {
        int j = jt * 32 + col;
#pragma unroll
        for (int r = 0; r < 16; r++) {
            int node = nb + (r & 3) + 8 * (r >> 2) + 4 * half;
            if (node < N_NODES) uvb[(size_t)node * 64 + j] = f2bf(acc[jt][r]);
        }
    }
}

// ------- agg3 + head: out = relu(sum_nbr(u) + v + cb) . w2 + bfc2 -------
// 16 nodes/wave x 4 lanes x 16B (u-half = 64B = 1 request/edge). Pad x4 => maskless.
__global__ void agg3h_kernel(const ushort_t* __restrict__ uvb, const int* __restrict__ off,
                             const int* __restrict__ srcs, const float* __restrict__ cbp,
                             const float* __restrict__ w2p, const float* __restrict__ bfc2,
                             float* __restrict__ out) {
    int wid = (blockIdx.x * 256 + threadIdx.x) >> 6;   // wave id
    int lane = threadIdx.x & 63;
    int n = lane >> 2;                       // node sub 0..15
    unsigned c = lane & 3;                   // 16B chunk of the 64B u-half
    int node0 = wid * 16 + n;
    int node = (node0 < N_NODES) ? node0 : N_NODES - 1;
    int b = off[node], e = off[node + 1];
    float acc[8];
#pragma unroll
    for (int j = 0; j < 8; j++) acc[j] = 0.f;
    const uint4* rows = (const uint4*)uvb;   // 8 chunks per 128B row (incl. zero row N)
    for (int p = b; p < e; p += 4) {
        int4 s = *(const int4*)(srcs + p);   // p is 4-aligned (pad x4)
        uint4 A = rows[(unsigned)s.x * 8u + c];
        uint4 B = rows[(unsigned)s.y * 8u + c];
        uint4 C = rows[(unsigned)s.z * 8u + c];
        uint4 D = rows[(unsigned)s.w * 8u + c];
        upadd(acc, A);
        upadd(acc, B);
        upadd(acc, C);
        upadd(acc, D);
    }
    // own v (second 64B half of this node's row)
    uint4 V = rows[(size_t)node * 8u + 4u + c];
    float vv[8];
    vv[0] = __uint_as_float(V.x << 16);
    vv[1] = __uint_as_float(V.x & 0xffff0000u);
    vv[2] = __uint_as_float(V.y << 16);
    vv[3] = __uint_as_float(V.y & 0xffff0000u);
    vv[4] = __uint_as_float(V.z << 16);
    vv[5] = __uint_as_float(V.z & 0xffff0000u);
    vv[6] = __uint_as_float(V.w << 16);
    vv[7] = __uint_as_float(V.w & 0xffff0000u);
    float4 cba = ((const float4*)cbp)[c * 2];
    float4 cbb = ((const float4*)cbp)[c * 2 + 1];
    float4 w2a = ((const float4*)w2p)[c * 2];
    float4 w2b = ((const float4*)w2p)[c * 2 + 1];
    float s = 0.f, a;
    a = acc[0] + vv[0] + cba.x; s += (a > 0.f ? a : 0.f) * w2a.x;
    a = acc[1] + vv[1] + cba.y; s += (a > 0.f ? a : 0.f) * w2a.y;
    a = acc[2] + vv[2] + cba.z; s += (a > 0.f ? a : 0.f) * w2a.z;
    a = acc[3] + vv[3] + cba.w; s += (a > 0.f ? a : 0.f) * w2a.w;
    a = acc[4] + vv[4] + cbb.x; s += (a > 0.f ? a : 0.f) * w2b.x;
    a = acc[5] + vv[5] + cbb.y; s += (a > 0.f ? a : 0.f) * w2b.y;
    a = acc[6] + vv[6] + cbb.z; s += (a > 0.f ? a : 0.f) * w2b.z;
    a = acc[7] + vv[7] + cbb.w; s += (a > 0.f ? a : 0.f) * w2b.w;
    s += __shfl_xor(s, 1);
    s += __shfl_xor(s, 2);
    if (c == 0 && node0 < N_NODES) out[node0] = s + bfc2[0];
}

// ---------------- launch ----------------
extern "C" void kernel_launch(void* const* d_in, const int* in_sizes, int n_in,
                              void* d_out, int out_size, void* d_ws, size_t ws_size,
                              hipStream_t stream) {
    const float* x = (const float*)d_in[0];
    const int* ei = (const int*)d_in[1];
    const float* W1rel = (const float*)d_in[2];
    const float* b1 = (const float*)d_in[3];
    const float* W1root = (const float*)d_in[4];
    const float* W2rel = (const float*)d_in[5];
    const float* b2 = (const float*)d_in[6];
    const float* W2root = (const float*)d_in[7];
    const float* Wfc1 = (const float*)d_in[8];
    const float* bfc1 = (const float*)d_in[9];
    const float* Wfc2 = (const float*)d_in[10];
    const float* bfc2 = (const float*)d_in[11];
    float* out = (float*)d_out;

    // all offsets rounded to 256B so every buffer alignment is by construction
    char* ws = (char*)d_ws;
    size_t o = 0;
    auto alloc = [&](size_t bytes) {
        char* p = ws + o;
        o += (bytes + 255) & ~(size_t)255;
        return p;
    };
    int* deg = (int*)alloc((size_t)N_NODES * 4);
    int* off = (int*)alloc((size_t)(N_NODES + 1) * 4);
    int* bsums = (int*)alloc(4096);
    int* flag = (int*)alloc(256);
    int* rank = (int*)alloc((size_t)N_EDGES * 4);                    // 3.2 MB
    int* srcs = (int*)alloc((size_t)SRCS_CAP * 4);                   // 4.4 MB
    ushort_t* xb = (ushort_t*)alloc((size_t)(N_NODES + 1) * FIN * 2);   // 12.8 MB (+zero row)
    ushort_t* agg1b = (ushort_t*)alloc((size_t)N_NODES * FIN * 2);      // 12.8 MB
    ushort_t* h1b = (ushort_t*)alloc((size_t)N_NODES * HID * 2);        // 25.6 MB
    ushort_t* uvb = (ushort_t*)alloc((size_t)(N_NODES + 1) * 64 * 2);   // 12.8 MB (+zero row)
    ushort_t* Wb1 = (ushort_t*)alloc((size_t)HID * HID * 2);            // 32 KB
    ushort_t* Mb = (ushort_t*)alloc((size_t)64 * HID * 2);              // 16 KB
    float* cbp = (float*)alloc(32 * 4);
    float* w2p = (float*)alloc(32 * 4);

    const int GW = (N_NODES + 127) / 128;  // 782 blocks: 4 waves x 32 nodes
    const int GA1 = N_NODES / 32;          // 3125 blocks: 4 waves x 8 nodes
    const int GA3 = 1563;                  // ceil(ceil(100000/16)/4) blocks: 4 waves x 16 nodes

    init_kernel<<<1024, 256, 0, stream>>>(ei, x, W1rel, W1root, W2rel, W2root,
                                          b2, Wfc1, bfc1, Wfc2,
                                          deg, flag, srcs, xb, Wb1, Mb, cbp, w2p);
    hist_kernel<<<(N_EDGES + 255) / 256, 256, 0, stream>>>(ei, flag, deg, rank);
    scan1_kernel<<<NB1, 256, 0, stream>>>(deg, off, bsums);
    scan23_kernel<<<NB1, 256, 0, stream>>>(off, bsums);
    scatter_kernel<<<(N_EDGES + 255) / 256, 256, 0, stream>>>(ei, flag, off, rank, srcs);
    agg1_kernel<<<GA1, 256, 0, stream>>>(xb, off, srcs, agg1b);
    g1_kernel<<<GW, 256, 0, stream>>>(agg1b, xb, Wb1, b1, h1b);
    g2_kernel<<<GW, 256, 0, stream>>>(h1b, Mb, uvb);
    agg3h_kernel<<<GA3, 256, 0, stream>>>(uvb, off, srcs, cbp, w2p, bfc2, out);
}